// Round 1
// baseline (1005.509 us; speedup 1.0000x reference)
//
#include <hip/hip_runtime.h>
#include <math.h>

#define DIM_IN  500
#define DIM_HID 128
#define DIM_OUT 40

// ---------------- small generic matmul (weight fusion, tiny) ----------------
__global__ void mm_small(const float* __restrict__ A, const float* __restrict__ B,
                         float* __restrict__ C, int M, int K, int Nc) {
    int idx = blockIdx.x * blockDim.x + threadIdx.x;
    if (idx >= M * Nc) return;
    int i = idx / Nc, j = idx - i * Nc;
    float s = 0.f;
    for (int k = 0; k < K; ++k) s = fmaf(A[i * K + k], B[k * Nc + j], s);
    C[idx] = s;
}

// ---------------- degree / dinv ----------------
__global__ void degree_k(const int* __restrict__ col, float* __restrict__ deg, int E) {
    int e = blockIdx.x * blockDim.x + threadIdx.x;
    if (e < E) atomicAdd(&deg[col[e]], 1.0f);
}

__global__ void dinv_k(float* __restrict__ deg, int N) {
    int i = blockIdx.x * blockDim.x + threadIdx.x;
    if (i < N) deg[i] = rsqrtf(deg[i] + 1.0f);   // +1 = self loop; deg_hat >= 1 always
}

// ---------------- main GEMM: Y[N x 40] = X[N x 500] @ Wf[500 x 40] ----------------
#define GBM 1024   // rows per block
#define GKT 8      // K chunk
__global__ __launch_bounds__(256, 1) void gemm_x_wf(const float* __restrict__ X,
                                                    const float* __restrict__ Wf,
                                                    float* __restrict__ Y, int N) {
    __shared__ float As[GBM][GKT + 1];     // +1 pad: 2-way bank alias only (free)
    __shared__ float Ws[GKT][DIM_OUT];
    const int tid  = threadIdx.x;
    const int row0 = blockIdx.x * GBM;

    float acc[4][DIM_OUT];
#pragma unroll
    for (int i = 0; i < 4; ++i)
#pragma unroll
        for (int j = 0; j < DIM_OUT; ++j) acc[i][j] = 0.f;

    for (int k0 = 0; k0 < DIM_IN; k0 += GKT) {
        const int kt = min(GKT, DIM_IN - k0);   // 8, tail 4
        __syncthreads();
        // stage A: each thread 4 rows x kt floats (row stride 500*4B: 16B aligned, k0%4==0)
#pragma unroll
        for (int i = 0; i < 4; ++i) {
            int rl = tid + i * 256;
            int r  = row0 + rl;
            float4 v0 = make_float4(0.f, 0.f, 0.f, 0.f);
            float4 v1 = make_float4(0.f, 0.f, 0.f, 0.f);
            if (r < N) {
                const float4* src = reinterpret_cast<const float4*>(X + (size_t)r * DIM_IN + k0);
                v0 = src[0];
                if (kt == GKT) v1 = src[1];
            }
            As[rl][0] = v0.x; As[rl][1] = v0.y; As[rl][2] = v0.z; As[rl][3] = v0.w;
            As[rl][4] = v1.x; As[rl][5] = v1.y; As[rl][6] = v1.z; As[rl][7] = v1.w;
        }
        // stage W chunk
        for (int w = tid; w < kt * DIM_OUT; w += 256)
            Ws[w / DIM_OUT][w % DIM_OUT] = Wf[(size_t)(k0 + w / DIM_OUT) * DIM_OUT + (w % DIM_OUT)];
        __syncthreads();

        for (int kk = 0; kk < kt; ++kk) {       // dynamic bound (tail); acc idx stays static
            float a[4];
#pragma unroll
            for (int i = 0; i < 4; ++i) a[i] = As[tid + i * 256][kk];
#pragma unroll
            for (int j = 0; j < DIM_OUT; ++j) {
                float w = Ws[kk][j];            // wave-uniform broadcast read
#pragma unroll
                for (int i = 0; i < 4; ++i) acc[i][j] = fmaf(a[i], w, acc[i][j]);
            }
        }
    }
#pragma unroll
    for (int i = 0; i < 4; ++i) {
        int r = row0 + tid + i * 256;
        if (r < N) {
#pragma unroll
            for (int j = 0; j < DIM_OUT; ++j) Y[(size_t)r * DIM_OUT + j] = acc[i][j];
        }
    }
}

// ---------------- edge aggregation (d=40): Hout[col] += Hin[row] * dinv[row]*dinv[col] ----------------
#define EPB 64     // edges per block; 64*40 = 2560 = 10 * 256
__global__ void edge_agg40(const int* __restrict__ row, const int* __restrict__ col,
                           const float* __restrict__ dinv, const float* __restrict__ Hin,
                           float* __restrict__ Hout, int E) {
    __shared__ int   rL[EPB];
    __shared__ int   cL[EPB];
    __shared__ float nL[EPB];
    const int e0  = blockIdx.x * EPB;
    const int tid = threadIdx.x;
    if (tid < EPB) {
        int e = e0 + tid;
        if (e < E) {
            int r = row[e], c = col[e];
            rL[tid] = r; cL[tid] = c; nL[tid] = dinv[r] * dinv[c];
        } else {
            rL[tid] = -1;
        }
    }
    __syncthreads();
#pragma unroll
    for (int it = 0; it < (EPB * DIM_OUT) / 256; ++it) {
        int w  = it * 256 + tid;
        int el = w / DIM_OUT;
        int j  = w - el * DIM_OUT;
        int r  = rL[el];
        if (r >= 0) {
            float v = Hin[(size_t)r * DIM_OUT + j] * nL[el];
            atomicAdd(&Hout[(size_t)cL[el] * DIM_OUT + j], v);
        }
    }
}

// ---------------- self loop + broadcast bias: Hout[i] += Hin[i]*dinv[i]^2 + bias ----------------
__global__ void self_bias40(const float* __restrict__ Hin, float* __restrict__ Hout,
                            const float* __restrict__ dinv, const float* __restrict__ bias, int N) {
    int idx = blockIdx.x * blockDim.x + threadIdx.x;
    if (idx >= N * DIM_OUT) return;
    int i = idx / DIM_OUT;
    int j = idx - i * DIM_OUT;
    float d = dinv[i];
    float v = Hin[idx] * d * d;
    if (bias) v += bias[j];
    Hout[idx] += v;
}

// ---------------- log_softmax over 40 (one wave per row) + final bias b3 ----------------
__global__ void logsoftmax40(const float* __restrict__ Hin, const float* __restrict__ b3,
                             float* __restrict__ out, int N) {
    int wave = (blockIdx.x * blockDim.x + threadIdx.x) >> 6;
    int lane = threadIdx.x & 63;
    if (wave >= N) return;
    float x = 0.f, v = -INFINITY;
    if (lane < DIM_OUT) {
        x = Hin[(size_t)wave * DIM_OUT + lane] + b3[lane];
        v = x;
    }
#pragma unroll
    for (int o = 32; o; o >>= 1) v = fmaxf(v, __shfl_xor(v, o));
    float ex = (lane < DIM_OUT) ? expf(x - v) : 0.f;
    float s = ex;
#pragma unroll
    for (int o = 32; o; o >>= 1) s += __shfl_xor(s, o);
    if (lane < DIM_OUT) out[(size_t)wave * DIM_OUT + lane] = x - v - logf(s);
}

// ---------------- launch ----------------
extern "C" void kernel_launch(void* const* d_in, const int* in_sizes, int n_in,
                              void* d_out, int out_size, void* d_ws, size_t ws_size,
                              hipStream_t stream) {
    const float* x  = (const float*)d_in[0];
    const int*   ei = (const int*)d_in[1];
    const float* W1 = (const float*)d_in[2];
    const float* b1 = (const float*)d_in[3];
    const float* W2 = (const float*)d_in[4];
    const float* b2 = (const float*)d_in[5];
    const float* W3 = (const float*)d_in[6];
    const float* b3 = (const float*)d_in[7];
    float* out = (float*)d_out;

    const int N = in_sizes[0] / DIM_IN;
    const int E = in_sizes[1] / 2;
    const int* row = ei;       // edge_index[0]
    const int* col = ei + E;   // edge_index[1]

    char* wsp = (char*)d_ws;
    auto alloc = [&](size_t bytes) -> void* {
        void* p = wsp;
        wsp += (bytes + 255) & ~(size_t)255;
        return p;
    };
    float* dinv = (float*)alloc((size_t)N * 4);
    float* W12  = (float*)alloc((size_t)DIM_IN * DIM_HID * 4);
    float* Wf   = (float*)alloc((size_t)DIM_IN * DIM_OUT * 4);
    float* t1   = (float*)alloc((size_t)DIM_HID * 4);
    float* bp1  = (float*)alloc((size_t)DIM_OUT * 4);
    float* bp2  = (float*)alloc((size_t)DIM_OUT * 4);
    float* Y0   = (float*)alloc((size_t)N * DIM_OUT * 4);
    float* Y1   = (float*)alloc((size_t)N * DIM_OUT * 4);

    const size_t ybytes = (size_t)N * DIM_OUT * 4;

    // normalization
    hipMemsetAsync(dinv, 0, (size_t)N * 4, stream);
    degree_k<<<(E + 255) / 256, 256, 0, stream>>>(col, dinv, E);
    dinv_k<<<(N + 255) / 256, 256, 0, stream>>>(dinv, N);

    // weight fusion: Wf = W1@W2@W3; bp1 = b1@W2@W3; bp2 = b2@W3
    mm_small<<<(DIM_IN * DIM_HID + 255) / 256, 256, 0, stream>>>(W1, W2, W12, DIM_IN, DIM_HID, DIM_HID);
    mm_small<<<(DIM_IN * DIM_OUT + 255) / 256, 256, 0, stream>>>(W12, W3, Wf, DIM_IN, DIM_HID, DIM_OUT);
    mm_small<<<1, 256, 0, stream>>>(b1, W2, t1, 1, DIM_HID, DIM_HID);
    mm_small<<<1, 64, 0, stream>>>(t1, W3, bp1, 1, DIM_HID, DIM_OUT);
    mm_small<<<1, 64, 0, stream>>>(b2, W3, bp2, 1, DIM_HID, DIM_OUT);

    // Y0 = X @ Wf
    gemm_x_wf<<<(N + GBM - 1) / GBM, 256, 0, stream>>>(x, Wf, Y0, N);

    const int aggGrid  = (E + EPB - 1) / EPB;
    const int sbGrid   = (N * DIM_OUT + 255) / 256;

    // layer 1: Y1 = A_hat Y0 + bp1
    hipMemsetAsync(Y1, 0, ybytes, stream);
    edge_agg40<<<aggGrid, 256, 0, stream>>>(row, col, dinv, Y0, Y1, E);
    self_bias40<<<sbGrid, 256, 0, stream>>>(Y0, Y1, dinv, bp1, N);

    // layer 2: Y0 = A_hat Y1 + bp2
    hipMemsetAsync(Y0, 0, ybytes, stream);
    edge_agg40<<<aggGrid, 256, 0, stream>>>(row, col, dinv, Y1, Y0, E);
    self_bias40<<<sbGrid, 256, 0, stream>>>(Y1, Y0, dinv, bp2, N);

    // layer 3: Y1 = A_hat Y0   (b3 folded into log_softmax)
    hipMemsetAsync(Y1, 0, ybytes, stream);
    edge_agg40<<<aggGrid, 256, 0, stream>>>(row, col, dinv, Y0, Y1, E);
    self_bias40<<<sbGrid, 256, 0, stream>>>(Y0, Y1, dinv, nullptr, N);

    // out = log_softmax(Y1 + b3)
    logsoftmax40<<<(N + 3) / 4, 256, 0, stream>>>(Y1, b3, out, N);
}

// Round 2
// 683.917 us; speedup vs baseline: 1.4702x; 1.4702x over previous
//
#include <hip/hip_runtime.h>
#include <math.h>

#define DIM_IN  500
#define DIM_HID 128
#define DIM_OUT 40

// ---------------- small generic matmul (weight fusion, tiny) ----------------
__global__ void mm_small(const float* __restrict__ A, const float* __restrict__ B,
                         float* __restrict__ C, int M, int K, int Nc) {
    int idx = blockIdx.x * blockDim.x + threadIdx.x;
    if (idx >= M * Nc) return;
    int i = idx / Nc, j = idx - i * Nc;
    float s = 0.f;
    for (int k = 0; k < K; ++k) s = fmaf(A[i * K + k], B[k * Nc + j], s);
    C[idx] = s;
}

// ---------------- degree histogram (in-degree over col) ----------------
__global__ void degree_k(const int* __restrict__ col, unsigned* __restrict__ deg, int E) {
    int e = blockIdx.x * blockDim.x + threadIdx.x;
    if (e < E) atomicAdd(&deg[col[e]], 1u);
}

__global__ void dinv_k(const unsigned* __restrict__ deg, float* __restrict__ dinv, int N) {
    int i = blockIdx.x * blockDim.x + threadIdx.x;
    if (i < N) dinv[i] = rsqrtf((float)deg[i] + 1.0f);   // +1 = self loop
}

// ---------------- single-block exclusive scan over deg -> off, cur ----------------
__global__ __launch_bounds__(1024) void scan_block(const unsigned* __restrict__ deg,
                                                   unsigned* __restrict__ off,
                                                   unsigned* __restrict__ cur, int N) {
    const int t = threadIdx.x;             // 1024 threads = 16 waves
    const int lane = t & 63, wid = t >> 6;
    __shared__ unsigned wsum[16];
    __shared__ unsigned carry_s;
    if (t == 0) carry_s = 0;
    __syncthreads();
    for (int base = 0; base < N; base += 1024) {
        unsigned x = (base + t < N) ? deg[base + t] : 0u;
        unsigned v = x;                     // inclusive wave scan
#pragma unroll
        for (int o = 1; o < 64; o <<= 1) {
            unsigned u = __shfl_up(v, o);
            if (lane >= o) v += u;
        }
        if (lane == 63) wsum[wid] = v;
        __syncthreads();
        if (wid == 0) {
            unsigned w = (lane < 16) ? wsum[lane] : 0u;
#pragma unroll
            for (int o = 1; o < 16; o <<= 1) {
                unsigned u = __shfl_up(w, o);
                if (lane >= o) w += u;
            }
            if (lane < 16) wsum[lane] = w;  // inclusive wave totals
        }
        __syncthreads();
        unsigned waveoff = wid ? wsum[wid - 1] : 0u;
        unsigned excl = carry_s + waveoff + (v - x);
        if (base + t < N) { off[base + t] = excl; cur[base + t] = excl; }
        __syncthreads();
        if (t == 0) carry_s += wsum[15];
        __syncthreads();
    }
    if (t == 0) off[N] = carry_s;
}

// ---------------- scatter edges into CSR (by col); stores source rows ----------------
__global__ void scatter_k(const int* __restrict__ row, const int* __restrict__ col,
                          unsigned* __restrict__ cur, int* __restrict__ srow, int E) {
    int e = blockIdx.x * blockDim.x + threadIdx.x;
    if (e < E) {
        unsigned p = atomicAdd(&cur[col[e]], 1u);
        srow[p] = row[e];
    }
}

// ---------------- main GEMM: G0 = dinv .* (X @ Wf), thread-per-row ----------------
__global__ __launch_bounds__(256) void gemm_rows(const float* __restrict__ X,
                                                 const float* __restrict__ Wf,
                                                 const float* __restrict__ dinv,
                                                 float* __restrict__ G, int N) {
    int r = blockIdx.x * blockDim.x + threadIdx.x;
    if (r >= N) return;
    const float* xr = X + (size_t)r * DIM_IN;
    float acc[DIM_OUT];
#pragma unroll
    for (int j = 0; j < DIM_OUT; ++j) acc[j] = 0.f;

    for (int k0 = 0; k0 < DIM_IN; k0 += 4) {
        float4 x4 = *reinterpret_cast<const float4*>(xr + k0);
        const float* wrow = Wf + (size_t)k0 * DIM_OUT;   // wave-uniform -> scalar loads
#pragma unroll
        for (int j = 0; j < DIM_OUT; ++j) acc[j] = fmaf(x4.x, wrow[j], acc[j]);
#pragma unroll
        for (int j = 0; j < DIM_OUT; ++j) acc[j] = fmaf(x4.y, wrow[DIM_OUT + j], acc[j]);
#pragma unroll
        for (int j = 0; j < DIM_OUT; ++j) acc[j] = fmaf(x4.z, wrow[2 * DIM_OUT + j], acc[j]);
#pragma unroll
        for (int j = 0; j < DIM_OUT; ++j) acc[j] = fmaf(x4.w, wrow[3 * DIM_OUT + j], acc[j]);
    }
    float d = dinv[r];
    float* gr = G + (size_t)r * DIM_OUT;
#pragma unroll
    for (int j = 0; j < DIM_OUT; ++j) gr[j] = acc[j] * d;
}

// ---------------- aggregation: wave per node, CSR gather, no atomics ----------------
// in:  G = dinv .* h_l      out (FINAL=0): G' = dinv .* (dinv*(G[c]+sum G[r]) + bias)
//                           out (FINAL=1): log_softmax(dinv*(...) + bias)
template <int FINAL>
__global__ __launch_bounds__(256) void agg40(const unsigned* __restrict__ off,
                                             const int* __restrict__ srow,
                                             const float* __restrict__ dinv,
                                             const float* __restrict__ G,
                                             const float* __restrict__ bias,
                                             float* __restrict__ out, int N) {
    int c = (blockIdx.x * blockDim.x + threadIdx.x) >> 6;
    int lane = threadIdx.x & 63;
    if (c >= N) return;
    unsigned beg = off[c], end = off[c + 1];
    float acc = 0.f;
    if (lane < DIM_OUT) acc = G[(size_t)c * DIM_OUT + lane];     // self loop (g[c])
    for (unsigned e = beg; e < end; ++e) {
        int r = srow[e];                                          // wave-uniform scalar load
        if (lane < DIM_OUT) acc += G[(size_t)r * DIM_OUT + lane]; // coalesced 160B gather
    }
    float d = dinv[c];
    float h = d * acc + bias[lane < DIM_OUT ? lane : 0];
    if (!FINAL) {
        if (lane < DIM_OUT) out[(size_t)c * DIM_OUT + lane] = d * h;
    } else {
        float xv = (lane < DIM_OUT) ? h : -INFINITY;
        float m = xv;
#pragma unroll
        for (int o = 32; o; o >>= 1) m = fmaxf(m, __shfl_xor(m, o));
        float ex = (lane < DIM_OUT) ? expf(xv - m) : 0.f;
        float s = ex;
#pragma unroll
        for (int o = 32; o; o >>= 1) s += __shfl_xor(s, o);
        if (lane < DIM_OUT) out[(size_t)c * DIM_OUT + lane] = xv - m - logf(s);
    }
}

// ---------------- launch ----------------
extern "C" void kernel_launch(void* const* d_in, const int* in_sizes, int n_in,
                              void* d_out, int out_size, void* d_ws, size_t ws_size,
                              hipStream_t stream) {
    const float* x  = (const float*)d_in[0];
    const int*   ei = (const int*)d_in[1];
    const float* W1 = (const float*)d_in[2];
    const float* b1 = (const float*)d_in[3];
    const float* W2 = (const float*)d_in[4];
    const float* b2 = (const float*)d_in[5];
    const float* W3 = (const float*)d_in[6];
    const float* b3 = (const float*)d_in[7];
    float* out = (float*)d_out;

    const int N = in_sizes[0] / DIM_IN;
    const int E = in_sizes[1] / 2;
    const int* row = ei;       // edge_index[0]
    const int* col = ei + E;   // edge_index[1]

    char* wsp = (char*)d_ws;
    auto alloc = [&](size_t bytes) -> void* {
        void* p = wsp;
        wsp += (bytes + 255) & ~(size_t)255;
        return p;
    };
    unsigned* deg  = (unsigned*)alloc((size_t)N * 4);
    unsigned* off  = (unsigned*)alloc((size_t)(N + 1) * 4);
    unsigned* cur  = (unsigned*)alloc((size_t)N * 4);
    int*      srow = (int*)alloc((size_t)E * 4);
    float*    dinv = (float*)alloc((size_t)N * 4);
    float*    W12  = (float*)alloc((size_t)DIM_IN * DIM_HID * 4);
    float*    Wf   = (float*)alloc((size_t)DIM_IN * DIM_OUT * 4);
    float*    t1   = (float*)alloc((size_t)DIM_HID * 4);
    float*    bp1  = (float*)alloc((size_t)DIM_OUT * 4);
    float*    bp2  = (float*)alloc((size_t)DIM_OUT * 4);
    float*    G0   = (float*)alloc((size_t)N * DIM_OUT * 4);
    float*    G1   = (float*)alloc((size_t)N * DIM_OUT * 4);

    // ---- CSR build + normalization ----
    hipMemsetAsync(deg, 0, (size_t)N * 4, stream);
    degree_k<<<(E + 255) / 256, 256, 0, stream>>>(col, deg, E);
    scan_block<<<1, 1024, 0, stream>>>(deg, off, cur, N);
    dinv_k<<<(N + 255) / 256, 256, 0, stream>>>(deg, dinv, N);
    scatter_k<<<(E + 255) / 256, 256, 0, stream>>>(row, col, cur, srow, E);

    // ---- weight fusion: Wf = W1@W2@W3; bp1 = b1@W2@W3; bp2 = b2@W3 (biases are zero) ----
    mm_small<<<(DIM_IN * DIM_HID + 255) / 256, 256, 0, stream>>>(W1, W2, W12, DIM_IN, DIM_HID, DIM_HID);
    mm_small<<<(DIM_IN * DIM_OUT + 255) / 256, 256, 0, stream>>>(W12, W3, Wf, DIM_IN, DIM_HID, DIM_OUT);
    mm_small<<<1, 256, 0, stream>>>(b1, W2, t1, 1, DIM_HID, DIM_HID);
    mm_small<<<1, 64, 0, stream>>>(t1, W3, bp1, 1, DIM_HID, DIM_OUT);
    mm_small<<<1, 64, 0, stream>>>(b2, W3, bp2, 1, DIM_HID, DIM_OUT);

    // ---- G0 = dinv .* (X @ Wf) ----
    gemm_rows<<<(N + 255) / 256, 256, 0, stream>>>(x, Wf, dinv, G0, N);

    // ---- three aggregations (wave per node) ----
    const int aggGrid = (N * 64 + 255) / 256;
    agg40<0><<<aggGrid, 256, 0, stream>>>(off, srow, dinv, G0, bp1, G1, N);
    agg40<0><<<aggGrid, 256, 0, stream>>>(off, srow, dinv, G1, bp2, G0, N);
    agg40<1><<<aggGrid, 256, 0, stream>>>(off, srow, dinv, G0, b3, out, N);
}

// Round 3
// 590.991 us; speedup vs baseline: 1.7014x; 1.1572x over previous
//
#include <hip/hip_runtime.h>
#include <math.h>

#define DIM_IN  500
#define DIM_HID 128
#define DIM_OUT 40
#define NQ4     125   // DIM_IN / 4 float4s per row

// ---------------- small generic matmul (weight fusion, tiny) ----------------
__global__ void mm_small(const float* __restrict__ A, const float* __restrict__ B,
                         float* __restrict__ C, int M, int K, int Nc) {
    int idx = blockIdx.x * blockDim.x + threadIdx.x;
    if (idx >= M * Nc) return;
    int i = idx / Nc, j = idx - i * Nc;
    float s = 0.f;
    for (int k = 0; k < K; ++k) s = fmaf(A[i * K + k], B[k * Nc + j], s);
    C[idx] = s;
}

// ---------------- degree histogram (in-degree over col) ----------------
__global__ void degree_k(const int* __restrict__ col, unsigned* __restrict__ deg, int E) {
    int e = blockIdx.x * blockDim.x + threadIdx.x;
    if (e < E) atomicAdd(&deg[col[e]], 1u);
}

__global__ void dinv_k(const unsigned* __restrict__ deg, float* __restrict__ dinv, int N) {
    int i = blockIdx.x * blockDim.x + threadIdx.x;
    if (i < N) dinv[i] = rsqrtf((float)deg[i] + 1.0f);   // +1 = self loop
}

// ---------------- single-block exclusive scan over deg -> off, cur ----------------
__global__ __launch_bounds__(1024) void scan_block(const unsigned* __restrict__ deg,
                                                   unsigned* __restrict__ off,
                                                   unsigned* __restrict__ cur, int N) {
    const int t = threadIdx.x;             // 1024 threads = 16 waves
    const int lane = t & 63, wid = t >> 6;
    __shared__ unsigned wsum[16];
    __shared__ unsigned carry_s;
    if (t == 0) carry_s = 0;
    __syncthreads();
    for (int base = 0; base < N; base += 1024) {
        unsigned x = (base + t < N) ? deg[base + t] : 0u;
        unsigned v = x;                     // inclusive wave scan
#pragma unroll
        for (int o = 1; o < 64; o <<= 1) {
            unsigned u = __shfl_up(v, o);
            if (lane >= o) v += u;
        }
        if (lane == 63) wsum[wid] = v;
        __syncthreads();
        if (wid == 0) {
            unsigned w = (lane < 16) ? wsum[lane] : 0u;
#pragma unroll
            for (int o = 1; o < 16; o <<= 1) {
                unsigned u = __shfl_up(w, o);
                if (lane >= o) w += u;
            }
            if (lane < 16) wsum[lane] = w;  // inclusive wave totals
        }
        __syncthreads();
        unsigned waveoff = wid ? wsum[wid - 1] : 0u;
        unsigned excl = carry_s + waveoff + (v - x);
        if (base + t < N) { off[base + t] = excl; cur[base + t] = excl; }
        __syncthreads();
        if (t == 0) carry_s += wsum[15];
        __syncthreads();
    }
    if (t == 0) off[N] = carry_s;
}

// ---------------- scatter edges into CSR (by col); stores source rows ----------------
__global__ void scatter_k(const int* __restrict__ row, const int* __restrict__ col,
                          unsigned* __restrict__ cur, int* __restrict__ srow, int E) {
    int e = blockIdx.x * blockDim.x + threadIdx.x;
    if (e < E) {
        unsigned p = atomicAdd(&cur[col[e]], 1u);
        srow[p] = row[e];
    }
}

// ---------------- GEMM partial: P[ch][r][j] = X[r, chunk] @ Wf[chunk, j] ----------------
__global__ __launch_bounds__(256) void gemm_part(const float* __restrict__ X,
                                                 const float* __restrict__ Wf,
                                                 float* __restrict__ P,
                                                 int N, int perq) {
    const int r  = blockIdx.x * 256 + threadIdx.x;
    const int ch = blockIdx.y;
    if (r >= N) return;
    const int q0 = ch * perq;
    const int q1 = min(q0 + perq, NQ4);
    const float4* xr = reinterpret_cast<const float4*>(X + (size_t)r * DIM_IN);

    float acc[DIM_OUT];
#pragma unroll
    for (int j = 0; j < DIM_OUT; ++j) acc[j] = 0.f;

    float4 x4 = xr[q0];
    for (int q = q0; q < q1; ++q) {
        float4 nx = (q + 1 < q1) ? xr[q + 1] : x4;      // prefetch next iter's X
        const float* wrow = Wf + (size_t)q * 4 * DIM_OUT;  // block-uniform -> scalar loads
#pragma unroll
        for (int j = 0; j < DIM_OUT; ++j) {
            float a = acc[j];
            a = fmaf(x4.x, wrow[j],                a);
            a = fmaf(x4.y, wrow[DIM_OUT + j],      a);
            a = fmaf(x4.z, wrow[2 * DIM_OUT + j],  a);
            a = fmaf(x4.w, wrow[3 * DIM_OUT + j],  a);
            acc[j] = a;
        }
        x4 = nx;
    }
    float4* pr = reinterpret_cast<float4*>(P + (size_t)ch * N * DIM_OUT + (size_t)r * DIM_OUT);
#pragma unroll
    for (int v = 0; v < DIM_OUT / 4; ++v)
        pr[v] = make_float4(acc[4 * v], acc[4 * v + 1], acc[4 * v + 2], acc[4 * v + 3]);
}

// ---------------- reduce partials + scale: G[r][j] = dinv[r] * sum_ch P[ch][r][j] ----------------
__global__ __launch_bounds__(256) void reduce_scale(const float* __restrict__ P,
                                                    const float* __restrict__ dinv,
                                                    float* __restrict__ G, int N, int nch) {
    int idx = blockIdx.x * blockDim.x + threadIdx.x;      // over N * 10 float4s
    if (idx >= N * (DIM_OUT / 4)) return;
    int r = idx / (DIM_OUT / 4);
    const size_t plane = (size_t)N * DIM_OUT / 4;
    const float4* p = reinterpret_cast<const float4*>(P) + idx;
    float4 s = p[0];
    for (int c = 1; c < nch; ++c) {
        float4 v = p[c * plane];
        s.x += v.x; s.y += v.y; s.z += v.z; s.w += v.w;
    }
    float d = dinv[r];
    s.x *= d; s.y *= d; s.z *= d; s.w *= d;
    reinterpret_cast<float4*>(G)[idx] = s;
}

// ---------------- fallback direct GEMM (if ws too small for partials) ----------------
__global__ __launch_bounds__(256) void gemm_rows(const float* __restrict__ X,
                                                 const float* __restrict__ Wf,
                                                 const float* __restrict__ dinv,
                                                 float* __restrict__ G, int N) {
    int r = blockIdx.x * blockDim.x + threadIdx.x;
    if (r >= N) return;
    const float4* xr = reinterpret_cast<const float4*>(X + (size_t)r * DIM_IN);
    float acc[DIM_OUT];
#pragma unroll
    for (int j = 0; j < DIM_OUT; ++j) acc[j] = 0.f;
    for (int q = 0; q < NQ4; ++q) {
        float4 x4 = xr[q];
        const float* wrow = Wf + (size_t)q * 4 * DIM_OUT;
#pragma unroll
        for (int j = 0; j < DIM_OUT; ++j) {
            float a = acc[j];
            a = fmaf(x4.x, wrow[j], a);
            a = fmaf(x4.y, wrow[DIM_OUT + j], a);
            a = fmaf(x4.z, wrow[2 * DIM_OUT + j], a);
            a = fmaf(x4.w, wrow[3 * DIM_OUT + j], a);
            acc[j] = a;
        }
    }
    float d = dinv[r];
    float* gr = G + (size_t)r * DIM_OUT;
#pragma unroll
    for (int j = 0; j < DIM_OUT; ++j) gr[j] = acc[j] * d;
}

// ---------------- aggregation: wave per node, CSR gather, 4-way pipelined ----------------
template <int FINAL>
__global__ __launch_bounds__(256) void agg40(const unsigned* __restrict__ off,
                                             const int* __restrict__ srow,
                                             const float* __restrict__ dinv,
                                             const float* __restrict__ G,
                                             const float* __restrict__ bias,
                                             float* __restrict__ out, int N) {
    int c = (blockIdx.x * blockDim.x + threadIdx.x) >> 6;
    int lane = threadIdx.x & 63;
    if (c >= N) return;
    const int jl = (lane < DIM_OUT) ? lane : (DIM_OUT - 1);   // all lanes in-bounds
    unsigned beg = off[c], end = off[c + 1];
    float a0 = G[(size_t)c * DIM_OUT + jl];                   // self loop
    float a1 = 0.f, a2 = 0.f, a3 = 0.f;
    unsigned e = beg;
    for (; e + 4 <= end; e += 4) {                            // 4 gathers in flight
        int r0 = srow[e], r1 = srow[e + 1], r2 = srow[e + 2], r3 = srow[e + 3];
        a0 += G[(size_t)r0 * DIM_OUT + jl];
        a1 += G[(size_t)r1 * DIM_OUT + jl];
        a2 += G[(size_t)r2 * DIM_OUT + jl];
        a3 += G[(size_t)r3 * DIM_OUT + jl];
    }
    for (; e < end; ++e) a0 += G[(size_t)srow[e] * DIM_OUT + jl];
    float acc = (a0 + a1) + (a2 + a3);
    float d = dinv[c];
    float h = d * acc + bias[jl];
    if (!FINAL) {
        if (lane < DIM_OUT) out[(size_t)c * DIM_OUT + lane] = d * h;
    } else {
        float xv = (lane < DIM_OUT) ? h : -INFINITY;
        float m = xv;
#pragma unroll
        for (int o = 32; o; o >>= 1) m = fmaxf(m, __shfl_xor(m, o));
        float ex = (lane < DIM_OUT) ? expf(xv - m) : 0.f;
        float s = ex;
#pragma unroll
        for (int o = 32; o; o >>= 1) s += __shfl_xor(s, o);
        if (lane < DIM_OUT) out[(size_t)c * DIM_OUT + lane] = xv - m - logf(s);
    }
}

// ---------------- launch ----------------
extern "C" void kernel_launch(void* const* d_in, const int* in_sizes, int n_in,
                              void* d_out, int out_size, void* d_ws, size_t ws_size,
                              hipStream_t stream) {
    const float* x  = (const float*)d_in[0];
    const int*   ei = (const int*)d_in[1];
    const float* W1 = (const float*)d_in[2];
    const float* b1 = (const float*)d_in[3];
    const float* W2 = (const float*)d_in[4];
    const float* b2 = (const float*)d_in[5];
    const float* W3 = (const float*)d_in[6];
    const float* b3 = (const float*)d_in[7];
    float* out = (float*)d_out;

    const int N = in_sizes[0] / DIM_IN;
    const int E = in_sizes[1] / 2;
    const int* row = ei;       // edge_index[0]
    const int* col = ei + E;   // edge_index[1]

    char* wsp = (char*)d_ws;
    size_t used = 0;
    auto alloc = [&](size_t bytes) -> void* {
        void* p = wsp + used;
        used += (bytes + 255) & ~(size_t)255;
        return p;
    };
    unsigned* deg  = (unsigned*)alloc((size_t)N * 4);
    unsigned* off  = (unsigned*)alloc((size_t)(N + 1) * 4);
    unsigned* cur  = (unsigned*)alloc((size_t)N * 4);
    int*      srow = (int*)alloc((size_t)E * 4);
    float*    dinv = (float*)alloc((size_t)N * 4);
    float*    W12  = (float*)alloc((size_t)DIM_IN * DIM_HID * 4);
    float*    Wf   = (float*)alloc((size_t)DIM_IN * DIM_OUT * 4);
    float*    t1   = (float*)alloc((size_t)DIM_HID * 4);
    float*    bp1  = (float*)alloc((size_t)DIM_OUT * 4);
    float*    bp2  = (float*)alloc((size_t)DIM_OUT * 4);
    float*    G0   = (float*)alloc((size_t)N * DIM_OUT * 4 + 256);
    float*    G1   = (float*)alloc((size_t)N * DIM_OUT * 4 + 256);

    // pick K-split factor by remaining workspace
    const size_t plane = (size_t)N * DIM_OUT * 4;
    int nch = 1;
    float* P = nullptr;
    if (ws_size >= used + 4 * plane + 256) { nch = 4; P = (float*)alloc(4 * plane + 256); }
    else if (ws_size >= used + 2 * plane + 256) { nch = 2; P = (float*)alloc(2 * plane + 256); }

    // ---- CSR build + normalization ----
    hipMemsetAsync(deg, 0, (size_t)N * 4, stream);
    degree_k<<<(E + 255) / 256, 256, 0, stream>>>(col, deg, E);
    scan_block<<<1, 1024, 0, stream>>>(deg, off, cur, N);
    dinv_k<<<(N + 255) / 256, 256, 0, stream>>>(deg, dinv, N);
    scatter_k<<<(E + 255) / 256, 256, 0, stream>>>(row, col, cur, srow, E);

    // ---- weight fusion: Wf = W1@W2@W3; bp1 = b1@W2@W3; bp2 = b2@W3 ----
    mm_small<<<(DIM_IN * DIM_HID + 255) / 256, 256, 0, stream>>>(W1, W2, W12, DIM_IN, DIM_HID, DIM_HID);
    mm_small<<<(DIM_IN * DIM_OUT + 255) / 256, 256, 0, stream>>>(W12, W3, Wf, DIM_IN, DIM_HID, DIM_OUT);
    mm_small<<<1, 256, 0, stream>>>(b1, W2, t1, 1, DIM_HID, DIM_HID);
    mm_small<<<1, 64, 0, stream>>>(t1, W3, bp1, 1, DIM_HID, DIM_OUT);
    mm_small<<<1, 64, 0, stream>>>(b2, W3, bp2, 1, DIM_HID, DIM_OUT);

    // ---- G0 = dinv .* (X @ Wf) ----
    if (nch > 1) {
        int perq = (NQ4 + nch - 1) / nch;
        dim3 grid((N + 255) / 256, nch);
        gemm_part<<<grid, 256, 0, stream>>>(x, Wf, P, N, perq);
        reduce_scale<<<(N * (DIM_OUT / 4) + 255) / 256, 256, 0, stream>>>(P, dinv, G0, N, nch);
    } else {
        gemm_rows<<<(N + 255) / 256, 256, 0, stream>>>(x, Wf, dinv, G0, N);
    }

    // ---- three aggregations (wave per node) ----
    const int aggGrid = (N * 64 + 255) / 256;
    agg40<0><<<aggGrid, 256, 0, stream>>>(off, srow, dinv, G0, bp1, G1, N);
    agg40<0><<<aggGrid, 256, 0, stream>>>(off, srow, dinv, G1, bp2, G0, N);
    agg40<1><<<aggGrid, 256, 0, stream>>>(off, srow, dinv, G0, b3, out, N);
}

// Round 4
// 477.405 us; speedup vs baseline: 2.1062x; 1.2379x over previous
//
#include <hip/hip_runtime.h>
#include <math.h>

#define DIM_IN  500
#define DIM_HID 128
#define DIM_OUT 40
#define NQ4     125   // DIM_IN/4 float4s per row
#define MAXPERQ 32    // max q per K-chunk (LDS = 32*160*4 = 20 KB)

// ---------------- small generic matmul (weight fusion), 4-way k-unroll ----------------
__global__ void mm_small(const float* __restrict__ A, const float* __restrict__ B,
                         float* __restrict__ C, int M, int K, int Nc) {
    int idx = blockIdx.x * blockDim.x + threadIdx.x;
    if (idx >= M * Nc) return;
    int i = idx / Nc, j = idx - i * Nc;
    const float* a = A + (size_t)i * K;
    const float* b = B + j;
    float s0 = 0.f, s1 = 0.f, s2 = 0.f, s3 = 0.f;
    int k = 0;
    for (; k + 4 <= K; k += 4) {
        s0 = fmaf(a[k],     b[(size_t)k * Nc],       s0);
        s1 = fmaf(a[k + 1], b[(size_t)(k + 1) * Nc], s1);
        s2 = fmaf(a[k + 2], b[(size_t)(k + 2) * Nc], s2);
        s3 = fmaf(a[k + 3], b[(size_t)(k + 3) * Nc], s3);
    }
    for (; k < K; ++k) s0 = fmaf(a[k], b[(size_t)k * Nc], s0);
    C[idx] = (s0 + s1) + (s2 + s3);
}

// ---------------- degree histogram (in-degree over col) ----------------
__global__ void degree_k(const int* __restrict__ col, unsigned* __restrict__ deg, int E) {
    int e = blockIdx.x * blockDim.x + threadIdx.x;
    if (e < E) atomicAdd(&deg[col[e]], 1u);
}

__global__ void dinv_k(const unsigned* __restrict__ deg, float* __restrict__ dinv, int N) {
    int i = blockIdx.x * blockDim.x + threadIdx.x;
    if (i < N) dinv[i] = rsqrtf((float)deg[i] + 1.0f);   // +1 = self loop
}

// ---------------- single-block exclusive scan (4 elems/thread) ----------------
__global__ __launch_bounds__(1024) void scan_block4(const unsigned* __restrict__ deg,
                                                    unsigned* __restrict__ off,
                                                    unsigned* __restrict__ cur, int N) {
    const int t = threadIdx.x, lane = t & 63, wid = t >> 6;
    const int N4 = (N + 3) >> 2;
    __shared__ unsigned wsum[16];
    __shared__ unsigned carry_s;
    if (t == 0) carry_s = 0;
    __syncthreads();
    for (int base = 0; base < N4; base += 1024) {
        int i = base + t;
        unsigned d0 = 0, d1 = 0, d2 = 0, d3 = 0;
        if (4 * i + 3 < N) {
            uint4 d = reinterpret_cast<const uint4*>(deg)[i];
            d0 = d.x; d1 = d.y; d2 = d.z; d3 = d.w;
        } else if (4 * i < N) {
            d0 = deg[4 * i];
            if (4 * i + 1 < N) d1 = deg[4 * i + 1];
            if (4 * i + 2 < N) d2 = deg[4 * i + 2];
        }
        unsigned tsum = d0 + d1 + d2 + d3;
        unsigned v = tsum;
#pragma unroll
        for (int o = 1; o < 64; o <<= 1) {
            unsigned u = __shfl_up(v, o);
            if (lane >= o) v += u;
        }
        if (lane == 63) wsum[wid] = v;
        __syncthreads();
        if (wid == 0) {
            unsigned w = (lane < 16) ? wsum[lane] : 0u;
#pragma unroll
            for (int o = 1; o < 16; o <<= 1) {
                unsigned u = __shfl_up(w, o);
                if (lane >= o) w += u;
            }
            if (lane < 16) wsum[lane] = w;
        }
        __syncthreads();
        unsigned excl = carry_s + (wid ? wsum[wid - 1] : 0u) + (v - tsum);
        unsigned o0 = excl, o1 = o0 + d0, o2 = o1 + d1, o3 = o2 + d2;
        if (4 * i + 3 < N) {
            reinterpret_cast<uint4*>(off)[i] = make_uint4(o0, o1, o2, o3);
            reinterpret_cast<uint4*>(cur)[i] = make_uint4(o0, o1, o2, o3);
        } else if (4 * i < N) {
            off[4 * i] = o0; cur[4 * i] = o0;
            if (4 * i + 1 < N) { off[4 * i + 1] = o1; cur[4 * i + 1] = o1; }
            if (4 * i + 2 < N) { off[4 * i + 2] = o2; cur[4 * i + 2] = o2; }
        }
        __syncthreads();
        if (t == 0) carry_s += wsum[15];
        __syncthreads();
    }
    if (t == 0) off[N] = carry_s;
}

// ---------------- scatter edges into CSR (by col); stores source rows ----------------
__global__ void scatter_k(const int* __restrict__ row, const int* __restrict__ col,
                          unsigned* __restrict__ cur, int* __restrict__ srow, int E) {
    int e = blockIdx.x * blockDim.x + threadIdx.x;
    if (e < E) {
        unsigned p = atomicAdd(&cur[col[e]], 1u);
        srow[p] = row[e];
    }
}

// ---------------- GEMM partial, W in LDS, 2 rows/thread ----------------
// P[ch][r][:] = X[r, chunk] @ Wf[chunk, :]
__global__ __launch_bounds__(256) void gemm_part(const float* __restrict__ X,
                                                 const float* __restrict__ Wf,
                                                 float* __restrict__ P,
                                                 int N, int perq) {
    __shared__ float Ws[MAXPERQ * 4 * DIM_OUT];     // 20 KB
    const int tid = threadIdx.x;
    const int ch  = blockIdx.y;
    const int q0  = ch * perq;
    const int cnt = min(q0 + perq, NQ4) - q0;       // q-iterations this chunk

    // stage W chunk (cnt*160 floats), coalesced float4
    {
        const float4* wsrc = reinterpret_cast<const float4*>(Wf + (size_t)q0 * 4 * DIM_OUT);
        const int nv = cnt * DIM_OUT;               // float4 count
        for (int i = tid; i < nv; i += 256) reinterpret_cast<float4*>(Ws)[i] = wsrc[i];
    }
    __syncthreads();

    const int r0 = blockIdx.x * 512 + tid;
    const int r1 = r0 + 256;
    if (r0 >= N) return;
    const bool has1 = (r1 < N);
    const float4* xa = reinterpret_cast<const float4*>(X + (size_t)r0 * DIM_IN) + q0;
    const float4* xb = reinterpret_cast<const float4*>(X + (size_t)(has1 ? r1 : r0) * DIM_IN) + q0;

    float acc0[DIM_OUT], acc1[DIM_OUT];
#pragma unroll
    for (int j = 0; j < DIM_OUT; ++j) { acc0[j] = 0.f; acc1[j] = 0.f; }

    float4 a4 = xa[0], b4 = xb[0];
    for (int q = 0; q < cnt; ++q) {
        const int qn = (q + 1 < cnt) ? q + 1 : q;
        float4 na = xa[qn], nb = xb[qn];            // prefetch next X
        const float* w = Ws + q * 4 * DIM_OUT;
#pragma unroll
        for (int kk = 0; kk < 4; ++kk) {
            const float* wk = w + kk * DIM_OUT;
            const float av = (kk == 0) ? a4.x : (kk == 1) ? a4.y : (kk == 2) ? a4.z : a4.w;
            const float bv = (kk == 0) ? b4.x : (kk == 1) ? b4.y : (kk == 2) ? b4.z : b4.w;
#pragma unroll
            for (int j4 = 0; j4 < DIM_OUT / 4; ++j4) {
                float4 wv = *reinterpret_cast<const float4*>(wk + j4 * 4);   // LDS broadcast
                acc0[4 * j4]     = fmaf(av, wv.x, acc0[4 * j4]);
                acc0[4 * j4 + 1] = fmaf(av, wv.y, acc0[4 * j4 + 1]);
                acc0[4 * j4 + 2] = fmaf(av, wv.z, acc0[4 * j4 + 2]);
                acc0[4 * j4 + 3] = fmaf(av, wv.w, acc0[4 * j4 + 3]);
                acc1[4 * j4]     = fmaf(bv, wv.x, acc1[4 * j4]);
                acc1[4 * j4 + 1] = fmaf(bv, wv.y, acc1[4 * j4 + 1]);
                acc1[4 * j4 + 2] = fmaf(bv, wv.z, acc1[4 * j4 + 2]);
                acc1[4 * j4 + 3] = fmaf(bv, wv.w, acc1[4 * j4 + 3]);
            }
        }
        a4 = na; b4 = nb;
    }

    float4* plane = reinterpret_cast<float4*>(P + (size_t)ch * N * DIM_OUT);
#pragma unroll
    for (int v = 0; v < DIM_OUT / 4; ++v)
        plane[(size_t)r0 * (DIM_OUT / 4) + v] =
            make_float4(acc0[4 * v], acc0[4 * v + 1], acc0[4 * v + 2], acc0[4 * v + 3]);
    if (has1) {
#pragma unroll
        for (int v = 0; v < DIM_OUT / 4; ++v)
            plane[(size_t)r1 * (DIM_OUT / 4) + v] =
                make_float4(acc1[4 * v], acc1[4 * v + 1], acc1[4 * v + 2], acc1[4 * v + 3]);
    }
}

// ---------------- reduce partials + scale: G[r][j] = dinv[r] * sum_ch P[ch][r][j] ----------------
__global__ __launch_bounds__(256) void reduce_scale(const float* __restrict__ P,
                                                    const float* __restrict__ dinv,
                                                    float* __restrict__ G, int N, int nch) {
    int idx = blockIdx.x * blockDim.x + threadIdx.x;      // over N*10 float4s
    if (idx >= N * (DIM_OUT / 4)) return;
    int r = idx / (DIM_OUT / 4);
    const size_t plane = (size_t)N * (DIM_OUT / 4);
    const float4* p = reinterpret_cast<const float4*>(P) + idx;
    float4 s = p[0];
    for (int c = 1; c < nch; ++c) {
        float4 v = p[c * plane];
        s.x += v.x; s.y += v.y; s.z += v.z; s.w += v.w;
    }
    float d = dinv[r];
    s.x *= d; s.y *= d; s.z *= d; s.w *= d;
    reinterpret_cast<float4*>(G)[idx] = s;
}

// ---------------- fallback direct GEMM (ws too small for partials) ----------------
__global__ __launch_bounds__(256) void gemm_rows(const float* __restrict__ X,
                                                 const float* __restrict__ Wf,
                                                 const float* __restrict__ dinv,
                                                 float* __restrict__ G, int N) {
    int r = blockIdx.x * blockDim.x + threadIdx.x;
    if (r >= N) return;
    const float4* xr = reinterpret_cast<const float4*>(X + (size_t)r * DIM_IN);
    float acc[DIM_OUT];
#pragma unroll
    for (int j = 0; j < DIM_OUT; ++j) acc[j] = 0.f;
    for (int q = 0; q < NQ4; ++q) {
        float4 x4 = xr[q];
        const float* wrow = Wf + (size_t)q * 4 * DIM_OUT;
#pragma unroll
        for (int j = 0; j < DIM_OUT; ++j) {
            float a = acc[j];
            a = fmaf(x4.x, wrow[j], a);
            a = fmaf(x4.y, wrow[DIM_OUT + j], a);
            a = fmaf(x4.z, wrow[2 * DIM_OUT + j], a);
            a = fmaf(x4.w, wrow[3 * DIM_OUT + j], a);
            acc[j] = a;
        }
    }
    float d = dinv[r];
    float* gr = G + (size_t)r * DIM_OUT;
#pragma unroll
    for (int j = 0; j < DIM_OUT; ++j) gr[j] = acc[j] * d;
}

// ---------------- aggregation: thread per (node, float4); 64 chains/wave ----------------
// SCALED=1: out = d*(d*acc + bias)   (feeds next layer, pre-scaled)
// SCALED=0: out = d*acc              (last layer; b3 folded into logsoftmax)
template <int SCALED>
__global__ __launch_bounds__(256) void agg4(const unsigned* __restrict__ off,
                                            const int* __restrict__ srow,
                                            const float* __restrict__ dinv,
                                            const float4* __restrict__ G4,
                                            const float4* __restrict__ bias4,
                                            float4* __restrict__ out4, int N) {
    const int idx = blockIdx.x * blockDim.x + threadIdx.x;
    if (idx >= N * (DIM_OUT / 4)) return;
    const int c = idx / (DIM_OUT / 4);
    const int v = idx - c * (DIM_OUT / 4);
    const unsigned beg = off[c], end = off[c + 1];

    float4 a0 = G4[(size_t)c * (DIM_OUT / 4) + v];    // self loop
    float4 a1 = make_float4(0.f, 0.f, 0.f, 0.f);
    float4 a2 = make_float4(0.f, 0.f, 0.f, 0.f);
    float4 a3 = make_float4(0.f, 0.f, 0.f, 0.f);
    unsigned e = beg;
    for (; e + 4 <= end; e += 4) {                    // 4 gathers in flight per lane
        int r0 = srow[e], r1 = srow[e + 1], r2 = srow[e + 2], r3 = srow[e + 3];
        float4 g0 = G4[(size_t)r0 * (DIM_OUT / 4) + v];
        float4 g1 = G4[(size_t)r1 * (DIM_OUT / 4) + v];
        float4 g2 = G4[(size_t)r2 * (DIM_OUT / 4) + v];
        float4 g3 = G4[(size_t)r3 * (DIM_OUT / 4) + v];
        a0.x += g0.x; a0.y += g0.y; a0.z += g0.z; a0.w += g0.w;
        a1.x += g1.x; a1.y += g1.y; a1.z += g1.z; a1.w += g1.w;
        a2.x += g2.x; a2.y += g2.y; a2.z += g2.z; a2.w += g2.w;
        a3.x += g3.x; a3.y += g3.y; a3.z += g3.z; a3.w += g3.w;
    }
    for (; e < end; ++e) {
        float4 g = G4[(size_t)srow[e] * (DIM_OUT / 4) + v];
        a0.x += g.x; a0.y += g.y; a0.z += g.z; a0.w += g.w;
    }
    float4 acc = make_float4((a0.x + a1.x) + (a2.x + a3.x), (a0.y + a1.y) + (a2.y + a3.y),
                             (a0.z + a1.z) + (a2.z + a3.z), (a0.w + a1.w) + (a2.w + a3.w));
    const float d = dinv[c];
    float4 o;
    if (SCALED) {
        float4 b = bias4[v];
        o = make_float4(d * (d * acc.x + b.x), d * (d * acc.y + b.y),
                        d * (d * acc.z + b.z), d * (d * acc.w + b.w));
    } else {
        o = make_float4(d * acc.x, d * acc.y, d * acc.z, d * acc.w);
    }
    out4[(size_t)c * (DIM_OUT / 4) + v] = o;
}

// ---------------- log_softmax over 40 (wave per row) + final bias b3 ----------------
__global__ void logsoftmax40(const float* __restrict__ Hin, const float* __restrict__ b3,
                             float* __restrict__ out, int N) {
    int wave = (blockIdx.x * blockDim.x + threadIdx.x) >> 6;
    int lane = threadIdx.x & 63;
    if (wave >= N) return;
    float x = 0.f, v = -INFINITY;
    if (lane < DIM_OUT) {
        x = Hin[(size_t)wave * DIM_OUT + lane] + b3[lane];
        v = x;
    }
#pragma unroll
    for (int o = 32; o; o >>= 1) v = fmaxf(v, __shfl_xor(v, o));
    float ex = (lane < DIM_OUT) ? expf(x - v) : 0.f;
    float s = ex;
#pragma unroll
    for (int o = 32; o; o >>= 1) s += __shfl_xor(s, o);
    if (lane < DIM_OUT) out[(size_t)wave * DIM_OUT + lane] = x - v - logf(s);
}

// ---------------- launch ----------------
extern "C" void kernel_launch(void* const* d_in, const int* in_sizes, int n_in,
                              void* d_out, int out_size, void* d_ws, size_t ws_size,
                              hipStream_t stream) {
    const float* x  = (const float*)d_in[0];
    const int*   ei = (const int*)d_in[1];
    const float* W1 = (const float*)d_in[2];
    const float* b1 = (const float*)d_in[3];
    const float* W2 = (const float*)d_in[4];
    const float* b2 = (const float*)d_in[5];
    const float* W3 = (const float*)d_in[6];
    const float* b3 = (const float*)d_in[7];
    float* out = (float*)d_out;

    const int N = in_sizes[0] / DIM_IN;
    const int E = in_sizes[1] / 2;
    const int* row = ei;       // edge_index[0]
    const int* col = ei + E;   // edge_index[1]

    char* wsp = (char*)d_ws;
    size_t used = 0;
    auto alloc = [&](size_t bytes) -> void* {
        void* p = wsp + used;
        used += (bytes + 255) & ~(size_t)255;
        return p;
    };
    unsigned* deg  = (unsigned*)alloc((size_t)N * 4);
    unsigned* off  = (unsigned*)alloc((size_t)(N + 1) * 4);
    unsigned* cur  = (unsigned*)alloc((size_t)N * 4);
    int*      srow = (int*)alloc((size_t)E * 4);
    float*    dinv = (float*)alloc((size_t)N * 4);
    float*    W12  = (float*)alloc((size_t)DIM_IN * DIM_HID * 4);
    float*    Wf   = (float*)alloc((size_t)DIM_IN * DIM_OUT * 4);
    float*    t1   = (float*)alloc((size_t)DIM_HID * 4);
    float*    bp1  = (float*)alloc((size_t)DIM_OUT * 4);
    float*    bp2  = (float*)alloc((size_t)DIM_OUT * 4);
    float*    G0   = (float*)alloc((size_t)N * DIM_OUT * 4 + 256);
    float*    G1   = (float*)alloc((size_t)N * DIM_OUT * 4 + 256);

    // pick K-split factor by remaining workspace
    const size_t plane = (size_t)N * DIM_OUT * 4;
    int nch = 1;
    float* P = nullptr;
    if      (ws_size >= used + 8 * plane + 256) { nch = 8; P = (float*)alloc(8 * plane + 256); }
    else if (ws_size >= used + 4 * plane + 256) { nch = 4; P = (float*)alloc(4 * plane + 256); }
    else if (ws_size >= used + 2 * plane + 256) { nch = 2; P = (float*)alloc(2 * plane + 256); }

    // ---- CSR build + normalization ----
    hipMemsetAsync(deg, 0, (size_t)N * 4, stream);
    degree_k<<<(E + 255) / 256, 256, 0, stream>>>(col, deg, E);
    scan_block4<<<1, 1024, 0, stream>>>(deg, off, cur, N);
    dinv_k<<<(N + 255) / 256, 256, 0, stream>>>(deg, dinv, N);
    scatter_k<<<(E + 255) / 256, 256, 0, stream>>>(row, col, cur, srow, E);

    // ---- weight fusion: Wf = W1@W2@W3; bp1 = b1@W2@W3; bp2 = b2@W3 ----
    mm_small<<<(DIM_IN * DIM_HID + 255) / 256, 256, 0, stream>>>(W1, W2, W12, DIM_IN, DIM_HID, DIM_HID);
    mm_small<<<(DIM_IN * DIM_OUT + 255) / 256, 256, 0, stream>>>(W12, W3, Wf, DIM_IN, DIM_HID, DIM_OUT);
    mm_small<<<1, 256, 0, stream>>>(b1, W2, t1, 1, DIM_HID, DIM_HID);
    mm_small<<<1, 64, 0, stream>>>(t1, W3, bp1, 1, DIM_HID, DIM_OUT);
    mm_small<<<1, 64, 0, stream>>>(b2, W3, bp2, 1, DIM_HID, DIM_OUT);

    // ---- G0 = dinv .* (X @ Wf) ----
    if (nch > 1) {
        int perq = (NQ4 + nch - 1) / nch;           // <= MAXPERQ for nch >= 4
        dim3 grid((N + 511) / 512, nch);
        gemm_part<<<grid, 256, 0, stream>>>(x, Wf, P, N, perq);
        reduce_scale<<<(N * (DIM_OUT / 4) + 255) / 256, 256, 0, stream>>>(P, dinv, G0, N, nch);
    } else {
        gemm_rows<<<(N + 255) / 256, 256, 0, stream>>>(x, Wf, dinv, G0, N);
    }

    // ---- three aggregations (thread per node-quad) ----
    const int aggGrid = (N * (DIM_OUT / 4) + 255) / 256;
    agg4<1><<<aggGrid, 256, 0, stream>>>(off, srow, dinv, (const float4*)G0, (const float4*)bp1, (float4*)G1, N);
    agg4<1><<<aggGrid, 256, 0, stream>>>(off, srow, dinv, (const float4*)G1, (const float4*)bp2, (float4*)G0, N);
    agg4<0><<<aggGrid, 256, 0, stream>>>(off, srow, dinv, (const float4*)G0, nullptr, (float4*)G1, N);

    // ---- out = log_softmax(G1 + b3) ----
    logsoftmax40<<<(N + 3) / 4, 256, 0, stream>>>(G1, b3, out, N);
}